// Round 1
// baseline (754.457 us; speedup 1.0000x reference)
//
#include <hip/hip_runtime.h>

// FERNN cell: fold all rolls into gather indices; recurrent conv as implicit
// GEMM on bf16 MFMA (tolerance is 2% absmax -> bf16 safe, fp32 accumulate).
//
// Shapes: u_t[16,3,32,32] f32; h_prev[16,9,128,64,64] f32; action[16,2] i32;
//         W_u[128,3,3,3] f32; W_h[128,128,3,3] f32; out[16,9,128,64,64] f32.
//
// NOTE: reference rolls h_prev[:, i] with axis=(1,2) of [B,C,H,W] -> the
// per-velocity roll hits the CHANNEL axis (vy) and H axis (vx). We match it.

typedef __attribute__((ext_vector_type(8))) short short8;
typedef __attribute__((ext_vector_type(4))) float f32x4;

static __device__ __forceinline__ unsigned short f2bf(float f) {
  union { float f; unsigned u; } v; v.f = f;
  unsigned u = v.u;
  unsigned r = u + 0x7FFFu + ((u >> 16) & 1u);   // RTNE
  return (unsigned short)(r >> 16);
}

// ---------- prep: W_h [co][ci][kh][kw] f32 -> bf16 padded tiles ----------
// Aws layout: [khw 0..8][cib 0..3][co 0..127][40] (ci_in 0..31 used, 8 pad)
__global__ __launch_bounds__(256) void prep_wh(const float* __restrict__ Wh,
                                               unsigned short* __restrict__ Aws) {
  int t = blockIdx.x * 256 + threadIdx.x;   // 147456 threads exactly
  if (t >= 9 * 4 * 128 * 32) return;
  int ci_in = t & 31;
  int co    = (t >> 5) & 127;
  int cib   = (t >> 12) & 3;
  int khw   = t >> 14;
  int kh = khw / 3, kw = khw - kh * 3;
  int ci = cib * 32 + ci_in;
  float w = Wh[((co * 128 + ci) * 3 + kh) * 3 + kw];
  Aws[((size_t)(khw * 4 + cib) * 128 + co) * 40 + ci_in] = f2bf(w);
}

// ---------- encoder: circular 3x3 conv on the 32x32 window ----------
// grid 16*128 blocks: one (b, co) per block; 1024 px / 256 thr = 4 px each
__global__ __launch_bounds__(256) void enc_conv(const float* __restrict__ u_t,
                                                const float* __restrict__ Wu,
                                                float* __restrict__ uc) {
  __shared__ float su[3 * 32 * 32];
  const int b  = blockIdx.x >> 7;
  const int co = blockIdx.x & 127;
  for (int i = threadIdx.x; i < 3072; i += 256) su[i] = u_t[b * 3072 + i];
  __syncthreads();
  float wreg[27];
#pragma unroll
  for (int k = 0; k < 27; ++k) wreg[k] = Wu[co * 27 + k];
#pragma unroll
  for (int px = 0; px < 4; ++px) {
    int p = threadIdx.x + px * 256;
    int oh = p >> 5, ow = p & 31;
    float s = 0.f;
#pragma unroll
    for (int ci = 0; ci < 3; ++ci)
#pragma unroll
      for (int kh = 0; kh < 3; ++kh)
#pragma unroll
        for (int kw = 0; kw < 3; ++kw)
          s += wreg[ci * 9 + kh * 3 + kw] *
               su[ci * 1024 + ((oh + kh + 31) & 31) * 32 + ((ow + kw + 31) & 31)];
    uc[(size_t)(b * 128 + co) * 1024 + p] = s;
  }
}

// ---------- main: implicit-GEMM conv, 128x128 tile, 4 waves ----------
__global__ __launch_bounds__(256) void fernn_main(
    const float* __restrict__ h_prev,
    const int* __restrict__ action,
    const unsigned short* __restrict__ Aws,
    const float* __restrict__ uconv,
    float* __restrict__ out) {
  // padded stride 40 shorts (80 B): 16B-slot stride 5 is coprime with 8 ->
  // conflict-free ds_read_b128; staging b32 writes land 2 lanes/bank (free).
  __shared__ __align__(16) unsigned short Xs[4 * 64 * 40];  // 20480 B
  __shared__ __align__(16) unsigned short As[128 * 40];     // 10240 B

  const int tid  = threadIdx.x;
  const int bid  = blockIdx.x;
  const int tile = bid & 31;          // output rows 2*tile, 2*tile+1
  const int img  = bid >> 5;          // 0..143 = b*9 + v
  const int b    = img / 9;
  const int v    = img - b * 9;
  const int vx   = v / 3 - 1;
  const int vy   = v - (v / 3) * 3 - 1;
  const int ax   = action[2 * b];
  const int ay   = action[2 * b + 1];
  const int h0   = tile * 2;

  const int lane = tid & 63;
  const int wid  = tid >> 6;
  const int wr   = wid >> 1;          // wave M quadrant
  const int wc   = wid & 1;           // wave N quadrant = output row offset
  const int li   = lane & 15;
  const int lh   = lane >> 4;

  const float* __restrict__ Xg = h_prev + (size_t)img * (128 * 64 * 64);

  // staging lane constants: i=w low, j=cp low, wave id = w block
  const int sti   = tid & 15;
  const int stj   = (tid >> 4) & 3;
  const int sw    = (tid >> 6) * 16 + sti;        // w in [0,64)
  const int w_src = (sw + ax) & 63;
  const int hbase = h0 - 1 + ay - vx + 128;

  int a_off[4];
#pragma unroll
  for (int mi = 0; mi < 4; ++mi) {
    int co = wr * 64 + mi * 16 + li;
    a_off[mi] = co * 80 + lh * 16;    // frag: A[co][k=8*lh..+7]
  }

  f32x4 acc[4][4];
#pragma unroll
  for (int mi = 0; mi < 4; ++mi)
#pragma unroll
    for (int nj = 0; nj < 4; ++nj)
      acc[mi][nj] = (f32x4){0.f, 0.f, 0.f, 0.f};

  for (int cib = 0; cib < 4; ++cib) {
    // ---- stage X(cib): rows r=0..3 = h_shifted rows h0-1..h0+2 ----
#pragma unroll
    for (int it = 0; it < 16; ++it) {
      int r  = it >> 2;
      int cb = it & 3;
      int cp = cb * 4 + stj;                     // ci-pair 0..15
      int ci0  = cib * 32 + cp * 2;
      int cia  = (ci0 - vy + 128) & 127;         // channel roll (vy)
      int cib2 = (ci0 + 1 - vy + 128) & 127;
      int h_src = (hbase + r) & 63;              // H roll (ay - vx)
      float f0 = Xg[(size_t)cia * 4096 + h_src * 64 + w_src];
      float f1 = Xg[(size_t)cib2 * 4096 + h_src * 64 + w_src];
      unsigned pk = ((unsigned)f2bf(f1) << 16) | (unsigned)f2bf(f0);
      *(unsigned*)((char*)Xs + ((r * 64 + sw) * 80 + cp * 4)) = pk;
    }

#pragma unroll
    for (int khw = 0; khw < 9; ++khw) {
      const int kh = khw / 3;
      const int kw = khw - kh * 3;
      // ---- stage A(khw,cib): 10240 B, 5 x 8B per thread ----
      {
        const unsigned long long* __restrict__ Ag =
            (const unsigned long long*)(Aws + (size_t)(khw * 4 + cib) * 5120);
#pragma unroll
        for (int itc = 0; itc < 5; ++itc) {
          int c = itc * 256 + tid;
          *(unsigned long long*)((char*)As + c * 8) = Ag[c];
        }
      }
      __syncthreads();

      short8 af[4], bfr[4];
#pragma unroll
      for (int mi = 0; mi < 4; ++mi)
        af[mi] = *(const short8*)((const char*)As + a_off[mi]);
#pragma unroll
      for (int nj = 0; nj < 4; ++nj) {
        int col = (nj * 16 + li + kw + 63) & 63;  // (w + kw - 1) mod 64
        bfr[nj] = *(const short8*)((const char*)Xs +
                                   ((wc + kh) * 64 + col) * 80 + lh * 16);
      }
#pragma unroll
      for (int mi = 0; mi < 4; ++mi)
#pragma unroll
        for (int nj = 0; nj < 4; ++nj)
          acc[mi][nj] = __builtin_amdgcn_mfma_f32_16x16x32_bf16(
              af[mi], bfr[nj], acc[mi][nj], 0, 0, 0);
      __syncthreads();
    }
  }

  // ---- epilogue: + u_full (h,w < 32), ReLU, store f32 ----
  const size_t obase = (size_t)img * (128 * 4096);
  const int h = h0 + wc;
#pragma unroll
  for (int mi = 0; mi < 4; ++mi) {
#pragma unroll
    for (int nj = 0; nj < 4; ++nj) {
      int w = nj * 16 + li;
#pragma unroll
      for (int rg = 0; rg < 4; ++rg) {
        int co = wr * 64 + mi * 16 + lh * 4 + rg;   // D row = 4*lh + reg
        float val = acc[mi][nj][rg];
        if (h < 32 && w < 32)
          val += uconv[((size_t)(b * 128 + co) * 32 + h) * 32 + w];
        val = fmaxf(val, 0.f);
        out[obase + (size_t)co * 4096 + h * 64 + w] = val;
      }
    }
  }
}

extern "C" void kernel_launch(void* const* d_in, const int* in_sizes, int n_in,
                              void* d_out, int out_size, void* d_ws, size_t ws_size,
                              hipStream_t stream) {
  const float* u_t    = (const float*)d_in[0];
  const float* h_prev = (const float*)d_in[1];
  const int*   action = (const int*)d_in[2];
  const float* W_u    = (const float*)d_in[3];
  const float* W_h    = (const float*)d_in[4];
  float* out = (float*)d_out;

  // ws layout: [0, 8.39 MB) u_conv f32 [16][128][32][32]; then Aws bf16 padded
  float* uconv = (float*)d_ws;
  unsigned short* Aws =
      (unsigned short*)((char*)d_ws + (size_t)16 * 128 * 32 * 32 * 4);

  prep_wh<<<576, 256, 0, stream>>>(W_h, Aws);
  enc_conv<<<2048, 256, 0, stream>>>(u_t, W_u, uconv);
  fernn_main<<<4608, 256, 0, stream>>>(h_prev, action, Aws, uconv, out);
}